// Round 8
// baseline (193.413 us; speedup 1.0000x reference)
//
#include <hip/hip_runtime.h>
#include <hip/hip_bf16.h>
#include <cstdint>

typedef __bf16 bf16;
typedef bf16 bf16x4 __attribute__((ext_vector_type(4)));
typedef bf16 bf16x8 __attribute__((ext_vector_type(8)));
typedef float f32x4 __attribute__((ext_vector_type(4)));
typedef float f32x16 __attribute__((ext_vector_type(16)));

#define NTOK 4096   // B*T
#define DLBL 512    // D_LABEL
#define NLAB 50

__device__ inline bf16x8 cvt8(float4 a, float4 b) {
  bf16x8 r;
  r[0] = (bf16)a.x; r[1] = (bf16)a.y; r[2] = (bf16)a.z; r[3] = (bf16)a.w;
  r[4] = (bf16)b.x; r[5] = (bf16)b.y; r[6] = (bf16)b.z; r[7] = (bf16)b.w;
  return r;
}

// async global->LDS, 16B per lane; LDS dest = wave-uniform base + lane*16
__device__ __forceinline__ void gl16(const bf16* g, void* l) {
  __builtin_amdgcn_global_load_lds(
      (const __attribute__((address_space(1))) void*)g,
      (__attribute__((address_space(3))) void*)l, 16, 0, 0);
}

// ---------------------------------------------------------------------------
// Fused prep: blocks [0,256) dep-proj (natural out), [256,512) head-proj
// (gathered, natural out), [512,6912) convW. Both proj bodies identical
// modulo the row gather.
// ---------------------------------------------------------------------------
__device__ void proj_body(int bidx, const float* __restrict__ rows,
                          const int* __restrict__ hidx, int rowstride,
                          const float* __restrict__ Wp,
                          const float* __restrict__ bv,
                          bf16* __restrict__ outN, char* lds) {
  char* ldsA = lds;           // [128 tok][32 d], stride 80
  char* ldsB = lds + 10240;   // [64 e][32 d], stride 80
  const int tid = threadIdx.x, l = tid & 63, w = tid >> 6;
  const int tokbase = (bidx >> 3) * 128;
  const int ebase   = (bidx & 7) * 64;
  const int wr = w & 1, wc = w >> 1;
  f32x4 acc[4][2] = {};
  const int arow = tid >> 1, ahalf = tid & 1;
  const int brow = tid >> 2, bgr = tid & 3;
  const int flat = tokbase + arow;
  const int bb = flat >> 11;
  const int rv = hidx ? hidx[flat] + bb * rowstride : flat;
  const float* aS = rows + (size_t)rv * 1024 + ahalf * 16;
  const float* bS = Wp + (size_t)(ebase + brow) * 1024 + bgr * 8;
  const int lo = (l & 15) * 80 + (l >> 4) * 16;
  for (int kb = 0; kb < 1024; kb += 32) {
    float4 a0 = *(const float4*)(aS + kb);
    float4 a1 = *(const float4*)(aS + kb + 4);
    float4 a2 = *(const float4*)(aS + kb + 8);
    float4 a3 = *(const float4*)(aS + kb + 12);
    float4 b0 = *(const float4*)(bS + kb);
    float4 b1 = *(const float4*)(bS + kb + 4);
    *(bf16x8*)(ldsA + arow * 80 + ahalf * 32)      = cvt8(a0, a1);
    *(bf16x8*)(ldsA + arow * 80 + ahalf * 32 + 16) = cvt8(a2, a3);
    *(bf16x8*)(ldsB + brow * 80 + bgr * 16)        = cvt8(b0, b1);
    __syncthreads();
    bf16x8 aF[4], bF[2];
#pragma unroll
    for (int i = 0; i < 4; ++i) aF[i] = *(bf16x8*)(ldsA + (wr * 64 + i * 16) * 80 + lo);
#pragma unroll
    for (int j = 0; j < 2; ++j) bF[j] = *(bf16x8*)(ldsB + (wc * 32 + j * 16) * 80 + lo);
#pragma unroll
    for (int i = 0; i < 4; ++i)
#pragma unroll
      for (int j = 0; j < 2; ++j)
        acc[i][j] = __builtin_amdgcn_mfma_f32_16x16x32_bf16(aF[i], bF[j], acc[i][j], 0, 0, 0);
    __syncthreads();
  }
#pragma unroll
  for (int i = 0; i < 4; ++i)
#pragma unroll
    for (int j = 0; j < 2; ++j)
#pragma unroll
      for (int r = 0; r < 4; ++r) {
        int tg = tokbase + wr * 64 + i * 16 + (l >> 4) * 4 + r;
        int eg = ebase + wc * 32 + j * 16 + (l & 15);
        outN[(size_t)tg * DLBL + eg] = (bf16)(acc[i][j][r] + bv[eg]);
      }
}

__global__ __launch_bounds__(256) void prep_k(const float* __restrict__ W,
                                              bf16* __restrict__ Wb,
                                              const float* __restrict__ dep_W,
                                              const float* __restrict__ dep,
                                              const float* __restrict__ dep_b,
                                              bf16* __restrict__ depN,
                                              const float* __restrict__ head,
                                              const int* __restrict__ hidx,
                                              const float* __restrict__ head_W,
                                              const float* __restrict__ head_b,
                                              bf16* __restrict__ selB) {
  __shared__ char lds[15360];
  const int b = blockIdx.x;
  if (b < 256) {
    proj_body(b, dep, nullptr, 0, dep_W, dep_b, depN, lds);
  } else if (b < 512) {
    proj_body(b - 256, head, hidx, 2049, head_W, head_b, selB, lds);
  } else {
    int i = (b - 512) * 256 + threadIdx.x;
    const float4* s = (const float4*)W + (size_t)i * 2;
    float4 a = s[0], c = s[1];
    *(bf16x8*)(Wb + (size_t)i * 8) = cvt8(a, c);
  }
}

// ---------------------------------------------------------------------------
// Kernel 4 v8: r5's proven structure (128d x 256tok, BK=32, 3-buffer 72KB,
// 2 blocks/CU, counted vmcnt(3), 1 barrier/K-tile, 2-tile lead, setprio)
// with the MFMA shape switched to 32x32x16 (-17% matrix-pipe time, -50%
// MFMA instr issue; same LDS traffic: 8 ds_read_b128 per wave/K-tile for
// a 2x2 grid of 32x32 tiles, acc = 2x2 f32x16 = 64 regs).
//   Frag reads: row = l&31, k-chunk = (l>>5) ^ swz; s=1 chunk = s0 addr ^ 32.
//   Conflict-free per 8-lane phase group under the existing chunk-XOR image.
//   Epilogue: 32x32 C layout (col=l&31, row=(reg&3)+8*(reg>>2)+4*(l>>5));
//   dep_label read NATURAL as bf16x4 (8B) vecs; single shfl_xor(32);
//   cross-wd combine in LDS -> 4 partials.
// ---------------------------------------------------------------------------
__global__ __launch_bounds__(512, 2) void biaff_k(const bf16* __restrict__ Wb,
                                                  const bf16* __restrict__ sel,
                                                  const bf16* __restrict__ depN,
                                                  float* __restrict__ parts) {
  __shared__ char lds[73728];          // 3 x (A 8KB + B 16KB)
  const int tid = threadIdx.x, l = tid & 63, w = tid >> 6;

  // bijective XCD-aware decode (r5-proven): combo fast, tok slow.
  const int lin = blockIdx.x;
  const int xcd = lin & 7, idx = lin >> 3;   // idx 0..399
  const int sub = idx % 25;
  const int bx  = idx / 25;                  // tok tile 0..15
  const int combo = xcd * 25 + sub;          // 0..199
  const int n  = combo % 50;
  const int dz = combo / 50;                 // 0..3
  const int tokbase = bx * 256;
  const int dbase   = dz * 128;

  const int wd = w >> 2, wt = w & 3;         // wave tile: 64 d x 64 tok
  f32x16 acc[2][2] = {};                     // [ti d-half][tj tok-half]

  // staging (unchanged from r5): lane -> row l>>2, chunk l&3; source chunk
  // pre-swizzled so image carries chunk ^= ((row>>1)&3)
  const int srow = l >> 2;
  const int schunk = ((l & 3) ^ ((l >> 3) & 3)) * 8;
  const bf16* aG = Wb  + ((size_t)(n * DLBL + dbase + w * 16 + srow)) * DLBL + schunk;
  const bf16* bG = sel + ((size_t)(tokbase + w * 32 + srow)) * DLBL + schunk;
  const int aOff = w * 1024;                 // w*16 rows * 64B
  const int bOff = 8192 + w * 2048;          // w*32 rows * 64B

  // 32x32x16 frag reads: row r31 = l&31, base k-chunk l5 = l>>5 (xor-swz),
  // s=1 address = s=0 address ^ 32 (chunk bit1 flip commutes with the XOR).
  const int r31 = l & 31, l5 = l >> 5;
  const int xr = (r31 >> 1) & 3;
  const int cAoff = (wd * 64 + r31) * 64 + ((l5 ^ xr) * 16);
  const int cBoff = 8192 + (wt * 64 + r31) * 64 + ((l5 ^ xr) * 16);

#define STG(T) do { \
    const bf16* a_ = aG + (T) * 32; \
    const bf16* b_ = bG + (T) * 32; \
    char* la_ = lds + ((T) % 3) * 24576 + aOff; \
    char* lb_ = lds + ((T) % 3) * 24576 + bOff; \
    gl16(a_, la_); \
    gl16(b_, lb_); \
    gl16(b_ + 16 * DLBL, lb_ + 1024); \
  } while (0)
#define WAITV(N) asm volatile("s_waitcnt vmcnt(" #N ")" ::: "memory")
#define PHASE(T, DOSTG, DOWV3, DOWV0, DOBAR) do { \
    const char* base_ = lds + ((T) % 3) * 24576; \
    bf16x8 a00 = *(const bf16x8*)(base_ + cAoff); \
    bf16x8 a01 = *(const bf16x8*)(base_ + (cAoff ^ 32)); \
    bf16x8 a10 = *(const bf16x8*)(base_ + (cAoff + 2048)); \
    bf16x8 a11 = *(const bf16x8*)(base_ + ((cAoff + 2048) ^ 32)); \
    bf16x8 b00 = *(const bf16x8*)(base_ + cBoff); \
    bf16x8 b01 = *(const bf16x8*)(base_ + (cBoff ^ 32)); \
    bf16x8 b10 = *(const bf16x8*)(base_ + (cBoff + 2048)); \
    bf16x8 b11 = *(const bf16x8*)(base_ + ((cBoff + 2048) ^ 32)); \
    if (DOSTG) STG((T) + 2); \
    __builtin_amdgcn_s_setprio(1); \
    acc[0][0] = __builtin_amdgcn_mfma_f32_32x32x16_bf16(a00, b00, acc[0][0], 0, 0, 0); \
    acc[0][1] = __builtin_amdgcn_mfma_f32_32x32x16_bf16(a00, b10, acc[0][1], 0, 0, 0); \
    acc[1][0] = __builtin_amdgcn_mfma_f32_32x32x16_bf16(a10, b00, acc[1][0], 0, 0, 0); \
    acc[1][1] = __builtin_amdgcn_mfma_f32_32x32x16_bf16(a10, b10, acc[1][1], 0, 0, 0); \
    acc[0][0] = __builtin_amdgcn_mfma_f32_32x32x16_bf16(a01, b01, acc[0][0], 0, 0, 0); \
    acc[0][1] = __builtin_amdgcn_mfma_f32_32x32x16_bf16(a01, b11, acc[0][1], 0, 0, 0); \
    acc[1][0] = __builtin_amdgcn_mfma_f32_32x32x16_bf16(a11, b01, acc[1][0], 0, 0, 0); \
    acc[1][1] = __builtin_amdgcn_mfma_f32_32x32x16_bf16(a11, b11, acc[1][1], 0, 0, 0); \
    __builtin_amdgcn_s_setprio(0); \
    if (DOWV3) WAITV(3); \
    if (DOWV0) WAITV(0); \
    if (DOBAR) __builtin_amdgcn_s_barrier(); \
  } while (0)

  // prologue: stage tiles 0,1 (6 loads/wave); certify tile 0 (drain to 3)
  STG(0); STG(1);
  WAITV(3);
  __builtin_amdgcn_s_barrier();

  PHASE(0, 1, 1, 0, 1);  PHASE(1, 1, 1, 0, 1);  PHASE(2, 1, 1, 0, 1);
  PHASE(3, 1, 1, 0, 1);  PHASE(4, 1, 1, 0, 1);  PHASE(5, 1, 1, 0, 1);
  PHASE(6, 1, 1, 0, 1);  PHASE(7, 1, 1, 0, 1);  PHASE(8, 1, 1, 0, 1);
  PHASE(9, 1, 1, 0, 1);  PHASE(10, 1, 1, 0, 1); PHASE(11, 1, 1, 0, 1);
  PHASE(12, 1, 1, 0, 1); PHASE(13, 1, 1, 0, 1);
  PHASE(14, 0, 0, 1, 1);                      // no stage; certify tile 15
  PHASE(15, 0, 0, 0, 0);                      // final tile

#undef PHASE
#undef WAITV
#undef STG

  // ---- epilogue: p[tj] = sum_d H[d, t_tj] * dep_label[t_tj, d] ----
  // C layout: col = r31 (token), row = (reg&3) + 8*(reg>>2) + 4*l5 (d).
  float p0 = 0.f, p1 = 0.f;
  const bf16* dN0 = depN + (size_t)(tokbase + wt * 64 + r31) * DLBL
                    + dbase + wd * 64 + l5 * 4;
  const bf16* dN1 = dN0 + (size_t)32 * DLBL;
#pragma unroll
  for (int ti = 0; ti < 2; ++ti)
#pragma unroll
    for (int q = 0; q < 4; ++q) {
      bf16x4 v0 = *(const bf16x4*)(dN0 + ti * 32 + q * 8);
      bf16x4 v1 = *(const bf16x4*)(dN1 + ti * 32 + q * 8);
#pragma unroll
      for (int m = 0; m < 4; ++m) {
        p0 += acc[ti][0][q * 4 + m] * (float)v0[m];
        p1 += acc[ti][1][q * 4 + m] * (float)v1[m];
      }
    }
  p0 += __shfl_xor(p0, 32);
  p1 += __shfl_xor(p1, 32);

  // cross-wd combine in LDS -> one partial per dz
  __syncthreads();
  float* lf = (float*)lds;
  if (wd == 1 && l < 32) {
    lf[(w - 4) * 64 + l]      = p0;
    lf[(w - 4) * 64 + 32 + l] = p1;
  }
  __syncthreads();
  if (wd == 0 && l < 32) {
    p0 += lf[w * 64 + l];
    p1 += lf[w * 64 + 32 + l];
    const size_t tg0 = tokbase + wt * 64 + r31;
    parts[(size_t)dz * 204800 + tg0 * NLAB + n]        = p0;
    parts[(size_t)dz * 204800 + (tg0 + 32) * NLAB + n] = p1;
  }
}

// ---------------------------------------------------------------------------
// Kernel 5: sum the 4 dz-partials + bias -> logits [4096][50] f32
// ---------------------------------------------------------------------------
__global__ __launch_bounds__(256) void fin_k(const float* __restrict__ parts,
                                             const float* __restrict__ bias,
                                             float* __restrict__ out) {
  int i = blockIdx.x * 256 + threadIdx.x;
  float v = 0.f;
#pragma unroll
  for (int q = 0; q < 4; ++q) v += parts[(size_t)q * 204800 + i];
  out[i] = v + bias[i % NLAB];
}

// ---------------------------------------------------------------------------
extern "C" void kernel_launch(void* const* d_in, const int* in_sizes, int n_in,
                              void* d_out, int out_size, void* d_ws, size_t ws_size,
                              hipStream_t stream) {
  const float* dep    = (const float*)d_in[0];
  const float* head   = (const float*)d_in[1];
  const int*   hidx   = (const int*)d_in[2];
  const float* dep_W  = (const float*)d_in[4];
  const float* dep_b  = (const float*)d_in[5];
  const float* head_W = (const float*)d_in[6];
  const float* head_b = (const float*)d_in[7];
  const float* W      = (const float*)d_in[8];
  const float* bias   = (const float*)d_in[9];
  float* out = (float*)d_out;

  char* ws = (char*)d_ws;
  bf16*  Wb    = (bf16*)(ws);
  bf16*  depN  = (bf16*)(ws + 26214400);
  bf16*  selB  = (bf16*)(ws + 30408704);
  float* parts = (float*)(ws + 34603008);
  if (ws_size < (size_t)37879808) return;

  hipLaunchKernelGGL(prep_k, dim3(6912), dim3(256), 0, stream,
                     W, Wb, dep_W, dep, dep_b, depN, head, hidx, head_W, head_b, selB);
  hipLaunchKernelGGL(biaff_k, dim3(3200), dim3(512), 0, stream, Wb, selB, depN, parts);
  hipLaunchKernelGGL(fin_k, dim3(800), dim3(256), 0, stream, parts, bias, out);
}